// Round 10
// baseline (207.593 us; speedup 1.0000x reference)
//
#include <hip/hip_runtime.h>
#include <stdint.h>

// Problem constants: B=32, N=1024, C=64, G=64
// ws layout (fp16): k_ws[32768*64] | vt_ws[32*64*1024] | ctr (4B @ byte 8 MB)
//
// R10 = R9 resubmission (infra failure, no signal).
// Single fused kernel (proj + software grid barrier + flash attention).
// 512 blocks x 256 thr, 64 KB LDS, __launch_bounds__(256,2) -> exactly
// 2 blocks/CU x 256 CU = 512 co-resident => atomic grid barrier is safe.
// q never leaves LDS (same block computes and consumes its q-tile).

typedef __attribute__((ext_vector_type(4))) float    floatx4;
typedef __attribute__((ext_vector_type(8))) _Float16 halfx8;

static __device__ __forceinline__ unsigned short f2h(float f) {
    union { _Float16 h; unsigned short u; } v; v.h = (_Float16)f;
    return v.u;
}
static __device__ __forceinline__ float h2f(unsigned short u) {
    union { unsigned short u; _Float16 h; } v; v.u = u;
    return (float)v.h;
}

__global__ __launch_bounds__(256, 2) void fused_attn_kernel(
    const float* __restrict__ x,
    const float* __restrict__ Wq, const float* __restrict__ bq,
    const float* __restrict__ Wk, const float* __restrict__ bk,
    const float* __restrict__ Wv, const float* __restrict__ bv,
    const int* __restrict__ valid_len,
    unsigned short* __restrict__ k_ws, unsigned short* __restrict__ vt_ws,
    unsigned int* ctr, float* __restrict__ out)
{
    // Phase A layout: [0,4096)=xs_hi (later q_lds, SURVIVES into phase B),
    // [4096,8192)=xs_lo (later k_lds), [8192,32768)= wT planes (vtmp aliases).
    // Phase B layout: [0,4096)=qs, [4096,12288)=kbuf[2], [12288,20480)=vbuf[2],
    // [20480,24576)=ps.  (indices in shorts)
    __shared__ __align__(16) unsigned short smem[8 * 4096];      // 64 KB
    float* vtmp = (float*)&smem[2 * 4096];

    const int XS_HI = 0, XS_LO = 4096;
    #define WT_OFF(i) (2 * 4096 + (i) * 4096)

    const int tid  = threadIdx.x;
    const int blk  = blockIdx.x;          // 0..511
    const int row0 = blk * 64;
    const int b    = blk >> 4;
    const int n0   = (blk & 15) * 64;
    const int lane = tid & 63;
    const int w    = tid >> 6;
    const int l15  = lane & 15;
    const int quad = lane >> 4;

    // ======================= Phase A: QKV projection =======================
    // --- stage x -> xs_hi/xs_lo (fp16 split, XOR-8 chunk swizzle) ---
#pragma unroll
    for (int i = 0; i < 2; ++i) {
        int id = i * 256 + tid;
        int r = id >> 3, c8 = id & 7;
        const float4* gp = (const float4*)(x + (row0 + r) * 64 + c8 * 8);
        float4 f0 = gp[0], f1 = gp[1];
        float fv[8] = { f0.x, f0.y, f0.z, f0.w, f1.x, f1.y, f1.z, f1.w };
        __align__(16) unsigned short thi[8], tlo[8];
#pragma unroll
        for (int j = 0; j < 8; ++j) {
            unsigned short hi = f2h(fv[j]);
            thi[j] = hi;
            tlo[j] = f2h(fv[j] - h2f(hi));
        }
        int idx = r * 64 + ((c8 ^ (r & 7)) * 8);
        *(uint4*)&smem[XS_HI + idx] = *(uint4*)thi;
        *(uint4*)&smem[XS_LO + idx] = *(uint4*)tlo;
    }
    // --- stage W^T hi/lo inline (R5-style; measured cost-neutral) ---
    {
        const float* Ws[3] = { Wq, Wk, Wv };
        int g = tid & 63, ci = tid >> 6;
#pragma unroll
        for (int wi = 0; wi < 3; ++wi) {
#pragma unroll
            for (int j = 0; j < 16; ++j) {
                int c = ci * 16 + j;
                float f = Ws[wi][c * 64 + g];
                unsigned short hi = f2h(f);
                unsigned short lo = f2h(f - h2f(hi));
                int idx = g * 64 + (((c >> 3) ^ (g & 7)) * 8) + (c & 7);
                smem[WT_OFF(wi * 2 + 0) + idx] = hi;
                smem[WT_OFF(wi * 2 + 1) + idx] = lo;
            }
        }
    }
    __syncthreads();

    // A-fragments (x) into registers
    const int arow = w * 16 + l15;
    const int aidx0 = arow * 64 + (((0 + quad) ^ (arow & 7)) * 8);
    const int aidx1 = arow * 64 + (((4 + quad) ^ (arow & 7)) * 8);
    halfx8 a_hi0 = *(const halfx8*)&smem[XS_HI + aidx0];
    halfx8 a_hi1 = *(const halfx8*)&smem[XS_HI + aidx1];
    halfx8 a_lo0 = *(const halfx8*)&smem[XS_LO + aidx0];
    halfx8 a_lo1 = *(const halfx8*)&smem[XS_LO + aidx1];

    __syncthreads();   // frags in regs -> xs region reusable as q_lds/k_lds

    unsigned short* q_lds = &smem[0];      // q stays here through phase B
    unsigned short* k_lds = &smem[4096];

    const float* biases[3] = { bq, bk, bv };
    floatx4 vacc[4];
#pragma unroll
    for (int wi = 0; wi < 3; ++wi) {
#pragma unroll
        for (int gs = 0; gs < 4; ++gs) {
            int g0 = gs * 16;
            float bias = biases[wi][g0 + l15];
            floatx4 acc = { bias, bias, bias, bias };
            int brow = g0 + l15;
            int bidx0 = brow * 64 + (((0 + quad) ^ (brow & 7)) * 8);
            int bidx1 = brow * 64 + (((4 + quad) ^ (brow & 7)) * 8);
            halfx8 b_hi0 = *(const halfx8*)&smem[WT_OFF(wi * 2 + 0) + bidx0];
            halfx8 b_hi1 = *(const halfx8*)&smem[WT_OFF(wi * 2 + 0) + bidx1];
            halfx8 b_lo0 = *(const halfx8*)&smem[WT_OFF(wi * 2 + 1) + bidx0];
            halfx8 b_lo1 = *(const halfx8*)&smem[WT_OFF(wi * 2 + 1) + bidx1];
            acc = __builtin_amdgcn_mfma_f32_16x16x32_f16(a_hi0, b_hi0, acc, 0, 0, 0);
            acc = __builtin_amdgcn_mfma_f32_16x16x32_f16(a_hi1, b_hi1, acc, 0, 0, 0);
            acc = __builtin_amdgcn_mfma_f32_16x16x32_f16(a_hi0, b_lo0, acc, 0, 0, 0);
            acc = __builtin_amdgcn_mfma_f32_16x16x32_f16(a_hi1, b_lo1, acc, 0, 0, 0);
            acc = __builtin_amdgcn_mfma_f32_16x16x32_f16(a_lo0, b_hi0, acc, 0, 0, 0);
            acc = __builtin_amdgcn_mfma_f32_16x16x32_f16(a_lo1, b_hi1, acc, 0, 0, 0);
            if (wi < 2) {
                unsigned short* dst = (wi == 0) ? q_lds : k_lds;
                int c8 = gs * 2 + (l15 >> 3);
#pragma unroll
                for (int r = 0; r < 4; ++r) {
                    int row = w * 16 + quad * 4 + r;   // wave-private rows
                    dst[row * 64 + ((c8 ^ (row & 7)) * 8) + (l15 & 7)] = f2h(acc[r]);
                }
            } else {
                vacc[gs] = acc;
            }
        }
    }

    __syncthreads();   // MFMAs done (wT free for vtmp), q/k LDS complete

    // --- coalesced k store (q stays in LDS) ---
#pragma unroll
    for (int i = 0; i < 2; ++i) {
        int id = i * 256 + tid;
        int r = id >> 3, c8 = id & 7;
        int sidx = r * 64 + ((c8 ^ (r & 7)) * 8);
        *(uint4*)(k_ws + (row0 + r) * 64 + c8 * 8) = *(const uint4*)&k_lds[sidx];
    }

    // --- v transpose through fp32 LDS (vtmp aliases wT region) ---
#pragma unroll
    for (int gs = 0; gs < 4; ++gs) {
#pragma unroll
        for (int r = 0; r < 4; ++r) {
            int nl = w * 16 + quad * 4 + r;
            vtmp[(gs * 16 + l15) * 65 + nl] = vacc[gs][r];
        }
    }
    __syncthreads();
    {
        int g = tid >> 2, c4 = tid & 3;
        __align__(16) unsigned short tmp[16];
#pragma unroll
        for (int j = 0; j < 16; ++j) tmp[j] = f2h(vtmp[g * 65 + c4 * 16 + j]);
        unsigned short* dst = vt_ws + (b * 64 + g) * 1024 + n0 + c4 * 16;
        *(uint4*)(dst)     = ((uint4*)tmp)[0];
        *(uint4*)(dst + 8) = ((uint4*)tmp)[1];
    }
    #undef WT_OFF

    // ================= device-wide barrier (all blocks resident) ===========
    __threadfence();                       // release k_ws/vt_ws stores (agent)
    __syncthreads();
    if (tid == 0) {
        atomicAdd(ctr, 1u);
        while (atomicAdd(ctr, 0u) < gridDim.x)
            __builtin_amdgcn_s_sleep(2);
    }
    __syncthreads();
    __threadfence();                       // acquire: invalidate stale caches

    // ======================= Phase B: flash attention ======================
    unsigned short* qs    = &smem[0];          // preserved q tile
    unsigned short* kbufA = &smem[4096];
    unsigned short* kbufB = &smem[8192];
    unsigned short* vbufA = &smem[12288];
    unsigned short* vbufB = &smem[16384];
    unsigned short* ps    = &smem[20480];      // 4 waves x 1024

    const int r_a  = tid >> 3,          c8_a = tid & 7;
    const int r_b  = (256 + tid) >> 3,  c8_b = tid & 7;
    const int lidx_a = r_a * 64 + ((c8_a ^ (r_a & 7)) * 8);
    const int lidx_b = r_b * 64 + ((c8_b ^ (r_b & 7)) * 8);

    const int vl    = valid_len[b];
    const int nt    = (vl == 0) ? 16 : ((vl + 63) >> 6);   // vl==0 -> uniform softmax
    const int fullt = vl >> 6;

    const unsigned short* kbase = k_ws + (size_t)b * 1024 * 64;
    const unsigned short* vbase = vt_ws + (size_t)b * 64 * 1024;

    // prologue: K(0), V(0) into buf A
    uint4 kr0 = *(const uint4*)(kbase + r_a * 64 + c8_a * 8);
    uint4 kr1 = *(const uint4*)(kbase + r_b * 64 + c8_b * 8);
    uint4 vr0 = *(const uint4*)(vbase + r_a * 1024 + c8_a * 8);
    uint4 vr1 = *(const uint4*)(vbase + r_b * 1024 + c8_b * 8);
    *(uint4*)&kbufA[lidx_a] = kr0;
    *(uint4*)&kbufA[lidx_b] = kr1;
    *(uint4*)&vbufA[lidx_a] = vr0;
    *(uint4*)&vbufA[lidx_b] = vr1;

    __syncthreads();

    halfx8 aq0 = *(const halfx8*)&qs[arow * 64 + (((0 + quad) ^ (arow & 7)) * 8)];
    halfx8 aq1 = *(const halfx8*)&qs[arow * 64 + (((4 + quad) ^ (arow & 7)) * 8)];

    float m_r[4]    = { -INFINITY, -INFINITY, -INFINITY, -INFINITY };
    float l_lane[4] = { 0.f, 0.f, 0.f, 0.f };
    floatx4 o[4] = { {0,0,0,0}, {0,0,0,0}, {0,0,0,0}, {0,0,0,0} };

    for (int t = 0; t < nt; ++t) {
        bool pre = (t + 1) < nt;
        if (pre) {
            const unsigned short* kp = kbase + (t + 1) * 64 * 64;
            const unsigned short* vp = vbase + (t + 1) * 64;
            kr0 = *(const uint4*)(kp + r_a * 64 + c8_a * 8);
            kr1 = *(const uint4*)(kp + r_b * 64 + c8_b * 8);
            vr0 = *(const uint4*)(vp + r_a * 1024 + c8_a * 8);
            vr1 = *(const uint4*)(vp + r_b * 1024 + c8_b * 8);
        }
        if (t > 0) __syncthreads();        // buf[t&1] writes visible; t-1 reads drained
        if (pre) {
            unsigned short* kn = ((t + 1) & 1) ? kbufB : kbufA;
            unsigned short* vn = ((t + 1) & 1) ? vbufB : vbufA;
            *(uint4*)&kn[lidx_a] = kr0;
            *(uint4*)&kn[lidx_b] = kr1;
            *(uint4*)&vn[lidx_a] = vr0;
            *(uint4*)&vn[lidx_b] = vr1;
        }
        const unsigned short* ksb = (t & 1) ? kbufB : kbufA;
        const unsigned short* vsb = (t & 1) ? vbufB : vbufA;

        // ---- S = Q K^T ----
        floatx4 s[4];
#pragma unroll
        for (int sub = 0; sub < 4; ++sub) {
            int krow = sub * 16 + l15;
            halfx8 bk0 = *(const halfx8*)&ksb[krow * 64 + (((0 + quad) ^ (krow & 7)) * 8)];
            halfx8 bk1 = *(const halfx8*)&ksb[krow * 64 + (((4 + quad) ^ (krow & 7)) * 8)];
            floatx4 acc = { 0, 0, 0, 0 };
            acc = __builtin_amdgcn_mfma_f32_16x16x32_f16(aq0, bk0, acc, 0, 0, 0);
            acc = __builtin_amdgcn_mfma_f32_16x16x32_f16(aq1, bk1, acc, 0, 0, 0);
            s[sub] = acc;
        }
        if (t >= fullt) {
#pragma unroll
            for (int sub = 0; sub < 4; ++sub) {
                int key = t * 64 + sub * 16 + l15;
                if (key >= vl) { s[sub][0] = -1e6f; s[sub][1] = -1e6f; s[sub][2] = -1e6f; s[sub][3] = -1e6f; }
            }
        }

        // ---- online softmax: wave-consistent max; per-lane deferred sum ----
        float p[4][4];
        float alpha[4];
#pragma unroll
        for (int r = 0; r < 4; ++r) {
            float mx = fmaxf(fmaxf(s[0][r], s[1][r]), fmaxf(s[2][r], s[3][r]));
#pragma unroll
            for (int off = 1; off < 16; off <<= 1)
                mx = fmaxf(mx, __shfl_xor(mx, off, 64));
            float mnew = fmaxf(m_r[r], mx);
            alpha[r] = __expf(m_r[r] - mnew);      // exp(-inf)=0 on first tile
            float psum = 0.f;
#pragma unroll
            for (int sub = 0; sub < 4; ++sub) {
                float pv = __expf(s[sub][r] - mnew);
                p[sub][r] = pv;
                psum += pv;
            }
            l_lane[r] = l_lane[r] * alpha[r] + psum;
            m_r[r] = mnew;
        }
#pragma unroll
        for (int gs = 0; gs < 4; ++gs) {
            o[gs][0] *= alpha[0]; o[gs][1] *= alpha[1];
            o[gs][2] *= alpha[2]; o[gs][3] *= alpha[3];
        }

        // ---- P (D-layout) -> fp16 LDS (A-layout, wave-private) ----
        unsigned short* psw = &ps[w * 1024];
#pragma unroll
        for (int sub = 0; sub < 4; ++sub) {
            int c8 = sub * 2 + (l15 >> 3);
#pragma unroll
            for (int r = 0; r < 4; ++r) {
                int row = quad * 4 + r;
                psw[row * 64 + ((c8 ^ (row & 7)) * 8) + (l15 & 7)] = f2h(p[sub][r]);
            }
        }
        halfx8 ap0 = *(const halfx8*)&psw[l15 * 64 + (((0 + quad) ^ (l15 & 7)) * 8)];
        halfx8 ap1 = *(const halfx8*)&psw[l15 * 64 + (((4 + quad) ^ (l15 & 7)) * 8)];

        // ---- O += P V ----
#pragma unroll
        for (int gs = 0; gs < 4; ++gs) {
            int grow = gs * 16 + l15;
            halfx8 bv0 = *(const halfx8*)&vsb[grow * 64 + (((0 + quad) ^ (grow & 7)) * 8)];
            halfx8 bv1 = *(const halfx8*)&vsb[grow * 64 + (((4 + quad) ^ (grow & 7)) * 8)];
            o[gs] = __builtin_amdgcn_mfma_f32_16x16x32_f16(ap0, bv0, o[gs], 0, 0, 0);
            o[gs] = __builtin_amdgcn_mfma_f32_16x16x32_f16(ap1, bv1, o[gs], 0, 0, 0);
        }
    }

    // ---- final 16-lane sum butterfly, store ----
    float l[4];
#pragma unroll
    for (int r = 0; r < 4; ++r) {
        float ss = l_lane[r];
#pragma unroll
        for (int off = 1; off < 16; off <<= 1)
            ss += __shfl_xor(ss, off, 64);
        l[r] = ss;
    }
#pragma unroll
    for (int gs = 0; gs < 4; ++gs) {
#pragma unroll
        for (int r = 0; r < 4; ++r) {
            int row = row0 + w * 16 + quad * 4 + r;
            out[row * 64 + gs * 16 + l15] = o[gs][r] / l[r];
        }
    }
}

// ---------------------------------------------------------------------------
extern "C" void kernel_launch(void* const* d_in, const int* in_sizes, int n_in,
                              void* d_out, int out_size, void* d_ws, size_t ws_size,
                              hipStream_t stream) {
    const float* x    = (const float*)d_in[0];
    const int*   vlen = (const int*)  d_in[1];
    const float* Wq   = (const float*)d_in[2];
    const float* bq   = (const float*)d_in[3];
    const float* Wk   = (const float*)d_in[4];
    const float* bk   = (const float*)d_in[5];
    const float* Wv   = (const float*)d_in[6];
    const float* bv   = (const float*)d_in[7];
    float* out = (float*)d_out;

    unsigned short* k_ws  = (unsigned short*)d_ws;
    unsigned short* vt_ws = k_ws + 32768 * 64;
    unsigned int*   ctr   = (unsigned int*)((char*)d_ws +
                              (size_t)2 * (32768 * 64 + 32 * 64 * 1024));

    hipMemsetAsync(ctr, 0, sizeof(unsigned int), stream);   // graph-capturable
    fused_attn_kernel<<<512, 256, 0, stream>>>(
        x, Wq, bq, Wk, bk, Wv, bv, vlen, k_ws, vt_ws, ctr, out);
}

// Round 11
// 114.950 us; speedup vs baseline: 1.8059x; 1.8059x over previous
//
#include <hip/hip_runtime.h>
#include <stdint.h>

// Problem constants: B=32, N=1024, C=64, G=64
//
// R11: single kernel, NO grid barrier, NO workspace. Each block (b, n0)
// projects its own Q-tile once, then per K-tile t recomputes K(t), V(t)
// from x (redundant across the batch's 16 blocks, but cheap: MFMA has
// huge headroom and x re-reads hit L2/L3). R10's counters showed the
// RMW-spin grid barrier cost ~110 us (MfmaUtil 1.7%, kernel 90% idle).
//
// LDS (64 KB, shorts):
//   Q  [    0, 4096) q tile (A-layout staged), resident all phases
//   VS [ 4096, 8192) V^T tile [g][key]     (written T3, read T5)
//   XH [ 8192,12288) x_hi tile; aliased as PS (P matrix) in T4/T5
//   XL [12288,16384) x_lo tile; aliased as KL (k tile)   in T3/T4
//   WK0/WK1/WV0/WV1 [16384..32768) Wk/Wv hi+lo planes, resident
//   (prologue: Wq_hi lives in VS, Wq_lo in WK0, both freed by syncs)

typedef __attribute__((ext_vector_type(4))) float    floatx4;
typedef __attribute__((ext_vector_type(8))) _Float16 halfx8;

static __device__ __forceinline__ unsigned short f2h(float f) {
    union { _Float16 h; unsigned short u; } v; v.h = (_Float16)f;
    return v.u;
}
static __device__ __forceinline__ float h2f(unsigned short u) {
    union { unsigned short u; _Float16 h; } v; v.u = u;
    return (float)v.h;
}

// stage 64x64 fp32 rows [grow0, grow0+64) of x into split hi/lo fp16,
// XOR-8 chunk-swizzled. 2 chunks of 8 elems per thread.
static __device__ __forceinline__ void stage_x(
    unsigned short* xh, unsigned short* xl, const float* __restrict__ x,
    int grow0, int tid)
{
#pragma unroll
    for (int i = 0; i < 2; ++i) {
        int id = i * 256 + tid;
        int r = id >> 3, c8 = id & 7;
        const float4* gp = (const float4*)(x + (grow0 + r) * 64 + c8 * 8);
        float4 f0 = gp[0], f1 = gp[1];
        float fv[8] = { f0.x, f0.y, f0.z, f0.w, f1.x, f1.y, f1.z, f1.w };
        __align__(16) unsigned short thi[8], tlo[8];
#pragma unroll
        for (int j = 0; j < 8; ++j) {
            unsigned short hi = f2h(fv[j]);
            thi[j] = hi;
            tlo[j] = f2h(fv[j] - h2f(hi));
        }
        int idx = r * 64 + ((c8 ^ (r & 7)) * 8);
        *(uint4*)&xh[idx] = *(uint4*)thi;
        *(uint4*)&xl[idx] = *(uint4*)tlo;
    }
}

// stage W^T (64x64) hi/lo planes, swizzled; g=lane -> coalesced reads.
static __device__ __forceinline__ void stage_w(
    const float* __restrict__ W, unsigned short* hiDst, unsigned short* loDst,
    int tid)
{
    int g = tid & 63, ci = tid >> 6;
#pragma unroll
    for (int j = 0; j < 16; ++j) {
        int c = ci * 16 + j;
        float f = W[c * 64 + g];
        unsigned short hi = f2h(f);
        unsigned short lo = f2h(f - h2f(hi));
        int idx = g * 64 + (((c >> 3) ^ (g & 7)) * 8) + (c & 7);
        hiDst[idx] = hi;
        loDst[idx] = lo;
    }
}

// split-precision 64(rows)x64(cols) projection for this wave's 16 rows:
// acc[gs] = A * W^T[gs-block] + bias, A given as hi/lo fragments.
static __device__ __forceinline__ void proj16(
    halfx8 ah0, halfx8 ah1, halfx8 al0, halfx8 al1,
    const unsigned short* bh, const unsigned short* bl,
    const float* __restrict__ bias, int l15, int quad, floatx4* accOut)
{
#pragma unroll
    for (int gs = 0; gs < 4; ++gs) {
        int brow = gs * 16 + l15;
        float bb = bias[gs * 16 + l15];
        floatx4 acc = { bb, bb, bb, bb };
        int bidx0 = brow * 64 + (((0 + quad) ^ (brow & 7)) * 8);
        int bidx1 = brow * 64 + (((4 + quad) ^ (brow & 7)) * 8);
        halfx8 b_hi0 = *(const halfx8*)&bh[bidx0];
        halfx8 b_hi1 = *(const halfx8*)&bh[bidx1];
        halfx8 b_lo0 = *(const halfx8*)&bl[bidx0];
        halfx8 b_lo1 = *(const halfx8*)&bl[bidx1];
        acc = __builtin_amdgcn_mfma_f32_16x16x32_f16(ah0, b_hi0, acc, 0, 0, 0);
        acc = __builtin_amdgcn_mfma_f32_16x16x32_f16(ah1, b_hi1, acc, 0, 0, 0);
        acc = __builtin_amdgcn_mfma_f32_16x16x32_f16(ah0, b_lo0, acc, 0, 0, 0);
        acc = __builtin_amdgcn_mfma_f32_16x16x32_f16(ah1, b_lo1, acc, 0, 0, 0);
        acc = __builtin_amdgcn_mfma_f32_16x16x32_f16(al0, b_hi0, acc, 0, 0, 0);
        acc = __builtin_amdgcn_mfma_f32_16x16x32_f16(al1, b_hi1, acc, 0, 0, 0);
        accOut[gs] = acc;
    }
}

__global__ __launch_bounds__(256, 2) void fused_attn_kernel(
    const float* __restrict__ x,
    const float* __restrict__ Wq, const float* __restrict__ bq,
    const float* __restrict__ Wk, const float* __restrict__ bk,
    const float* __restrict__ Wv, const float* __restrict__ bv,
    const int* __restrict__ valid_len, float* __restrict__ out)
{
    __shared__ __align__(16) unsigned short smem[8 * 4096];   // 64 KB

    unsigned short* Q   = &smem[0];
    unsigned short* VS  = &smem[4096];
    unsigned short* XH  = &smem[8192];
    unsigned short* XL  = &smem[12288];
    unsigned short* WK0 = &smem[16384];
    unsigned short* WK1 = &smem[20480];
    unsigned short* WV0 = &smem[24576];
    unsigned short* WV1 = &smem[28672];
    unsigned short* PS  = XH;   // alias (valid T4/T5)
    unsigned short* KL  = XL;   // alias (valid T3/T4)

    const int tid  = threadIdx.x;
    const int blk  = blockIdx.x;          // 0..511
    const int row0 = blk * 64;            // b*1024 + n0
    const int b    = blk >> 4;
    const int lane = tid & 63;
    const int w    = tid >> 6;
    const int l15  = lane & 15;
    const int quad = lane >> 4;
    const int arow = w * 16 + l15;
    const int aidx0 = arow * 64 + (((0 + quad) ^ (arow & 7)) * 8);
    const int aidx1 = arow * 64 + (((4 + quad) ^ (arow & 7)) * 8);

    const int vl    = valid_len[b];
    const int nt    = (vl == 0) ? 16 : ((vl + 63) >> 6);   // vl==0 -> uniform softmax
    const int fullt = vl >> 6;

    // ===================== Prologue: project own Q-tile =====================
    stage_x(XH, XL, x, row0, tid);
    stage_w(Wq, VS, WK0, tid);            // Wq_hi -> VS, Wq_lo -> WK0 (temp)
    __syncthreads();                      // S_P1

    {
        halfx8 ah0 = *(const halfx8*)&XH[aidx0];
        halfx8 ah1 = *(const halfx8*)&XH[aidx1];
        halfx8 al0 = *(const halfx8*)&XL[aidx0];
        halfx8 al1 = *(const halfx8*)&XL[aidx1];
        floatx4 qacc[4];
        proj16(ah0, ah1, al0, al1, VS, WK0, bq, l15, quad, qacc);
        // q (D-layout) -> Q (A-layout staged, wave-private rows)
#pragma unroll
        for (int gs = 0; gs < 4; ++gs) {
            int c8 = gs * 2 + (l15 >> 3);
#pragma unroll
            for (int r = 0; r < 4; ++r) {
                int row = w * 16 + quad * 4 + r;
                Q[row * 64 + ((c8 ^ (row & 7)) * 8) + (l15 & 7)] = f2h(qacc[r][gs == 0 ? 0 : 0] * 0.f + qacc[gs][r]);
            }
        }
    }
    __syncthreads();                      // S_P2: Q written; VS/WK0/XH/XL reads done

    // resident W planes (overwrites Wq_lo in WK0 — safe post S_P2)
    stage_w(Wk, WK0, WK1, tid);
    stage_w(Wv, WV0, WV1, tid);
    // (visibility to T3 of tile 0 is covered by the loop's first two barriers)

    // own-wave Q rows -> A-fragments (only this wave's writes, ds-ordered)
    halfx8 aq0 = *(const halfx8*)&Q[aidx0];
    halfx8 aq1 = *(const halfx8*)&Q[aidx1];

    float m_r[4]    = { -INFINITY, -INFINITY, -INFINITY, -INFINITY };
    float l_lane[4] = { 0.f, 0.f, 0.f, 0.f };
    floatx4 o[4] = { {0,0,0,0}, {0,0,0,0}, {0,0,0,0}, {0,0,0,0} };

    // ========================= K-tile loop ==========================
    for (int t = 0; t < nt; ++t) {
        __syncthreads();                  // (a) prior readers of XH/XL/VS done
        stage_x(XH, XL, x, b * 1024 + t * 64, tid);   // T1
        __syncthreads();                  // (b) x tile visible

        // T2: x A-frags for this wave's 16 key rows
        halfx8 kxh0 = *(const halfx8*)&XH[aidx0];
        halfx8 kxh1 = *(const halfx8*)&XH[aidx1];
        halfx8 kxl0 = *(const halfx8*)&XL[aidx0];
        halfx8 kxl1 = *(const halfx8*)&XL[aidx1];
        __syncthreads();                  // (c) frag reads done; XL reusable as KL

        // T3: recompute K(t), V(t) tiles (split precision)
        {
            floatx4 kacc[4], vacc2[4];
            proj16(kxh0, kxh1, kxl0, kxl1, WK0, WK1, bk, l15, quad, kacc);
            proj16(kxh0, kxh1, kxl0, kxl1, WV0, WV1, bv, l15, quad, vacc2);
#pragma unroll
            for (int gs = 0; gs < 4; ++gs) {
                int c8 = gs * 2 + (l15 >> 3);
                int g  = gs * 16 + l15;
#pragma unroll
                for (int r = 0; r < 4; ++r) {
                    int key = w * 16 + quad * 4 + r;
                    // K: A-layout staged rows=key (wave-private rows)
                    KL[key * 64 + ((c8 ^ (key & 7)) * 8) + (l15 & 7)] = f2h(kacc[gs][r]);
                    // V^T: rows=g, swizzled chunks over key
                    VS[g * 64 + (((key >> 3) ^ (g & 7)) * 8) + (key & 7)] = f2h(vacc2[gs][r]);
                }
            }
        }
        __syncthreads();                  // (d) K/V tiles visible

        // T4: S = Q K^T
        floatx4 s[4];
#pragma unroll
        for (int sub = 0; sub < 4; ++sub) {
            int krow = sub * 16 + l15;
            halfx8 bk0 = *(const halfx8*)&KL[krow * 64 + (((0 + quad) ^ (krow & 7)) * 8)];
            halfx8 bk1 = *(const halfx8*)&KL[krow * 64 + (((4 + quad) ^ (krow & 7)) * 8)];
            floatx4 acc = { 0, 0, 0, 0 };
            acc = __builtin_amdgcn_mfma_f32_16x16x32_f16(aq0, bk0, acc, 0, 0, 0);
            acc = __builtin_amdgcn_mfma_f32_16x16x32_f16(aq1, bk1, acc, 0, 0, 0);
            s[sub] = acc;
        }
        if (t >= fullt) {
#pragma unroll
            for (int sub = 0; sub < 4; ++sub) {
                int key = t * 64 + sub * 16 + l15;
                if (key >= vl) { s[sub][0] = -1e6f; s[sub][1] = -1e6f; s[sub][2] = -1e6f; s[sub][3] = -1e6f; }
            }
        }

        // online softmax: wave-consistent max; per-lane deferred sum
        float p[4][4];
        float alpha[4];
#pragma unroll
        for (int r = 0; r < 4; ++r) {
            float mx = fmaxf(fmaxf(s[0][r], s[1][r]), fmaxf(s[2][r], s[3][r]));
#pragma unroll
            for (int off = 1; off < 16; off <<= 1)
                mx = fmaxf(mx, __shfl_xor(mx, off, 64));
            float mnew = fmaxf(m_r[r], mx);
            alpha[r] = __expf(m_r[r] - mnew);
            float psum = 0.f;
#pragma unroll
            for (int sub = 0; sub < 4; ++sub) {
                float pv = __expf(s[sub][r] - mnew);
                p[sub][r] = pv;
                psum += pv;
            }
            l_lane[r] = l_lane[r] * alpha[r] + psum;
            m_r[r] = mnew;
        }
#pragma unroll
        for (int gs = 0; gs < 4; ++gs) {
            o[gs][0] *= alpha[0]; o[gs][1] *= alpha[1];
            o[gs][2] *= alpha[2]; o[gs][3] *= alpha[3];
        }

        // P (D-layout) -> fp16 LDS (A-layout, wave-private region of PS)
        unsigned short* psw = &PS[w * 1024];
#pragma unroll
        for (int sub = 0; sub < 4; ++sub) {
            int c8 = sub * 2 + (l15 >> 3);
#pragma unroll
            for (int r = 0; r < 4; ++r) {
                int row = quad * 4 + r;
                psw[row * 64 + ((c8 ^ (row & 7)) * 8) + (l15 & 7)] = f2h(p[sub][r]);
            }
        }
        halfx8 ap0 = *(const halfx8*)&psw[l15 * 64 + (((0 + quad) ^ (l15 & 7)) * 8)];
        halfx8 ap1 = *(const halfx8*)&psw[l15 * 64 + (((4 + quad) ^ (l15 & 7)) * 8)];

        // T5: O += P V
#pragma unroll
        for (int gs = 0; gs < 4; ++gs) {
            int grow = gs * 16 + l15;
            halfx8 bv0 = *(const halfx8*)&VS[grow * 64 + (((0 + quad) ^ (grow & 7)) * 8)];
            halfx8 bv1 = *(const halfx8*)&VS[grow * 64 + (((4 + quad) ^ (grow & 7)) * 8)];
            o[gs] = __builtin_amdgcn_mfma_f32_16x16x32_f16(ap0, bv0, o[gs], 0, 0, 0);
            o[gs] = __builtin_amdgcn_mfma_f32_16x16x32_f16(ap1, bv1, o[gs], 0, 0, 0);
        }
    }

    // ---- final 16-lane sum butterfly, store ----
    float l[4];
#pragma unroll
    for (int r = 0; r < 4; ++r) {
        float ss = l_lane[r];
#pragma unroll
        for (int off = 1; off < 16; off <<= 1)
            ss += __shfl_xor(ss, off, 64);
        l[r] = ss;
    }
#pragma unroll
    for (int gs = 0; gs < 4; ++gs) {
#pragma unroll
        for (int r = 0; r < 4; ++r) {
            int row = row0 + w * 16 + quad * 4 + r;
            out[row * 64 + gs * 16 + l15] = o[gs][r] / l[r];
        }
    }
}

// ---------------------------------------------------------------------------
extern "C" void kernel_launch(void* const* d_in, const int* in_sizes, int n_in,
                              void* d_out, int out_size, void* d_ws, size_t ws_size,
                              hipStream_t stream) {
    const float* x    = (const float*)d_in[0];
    const int*   vlen = (const int*)  d_in[1];
    const float* Wq   = (const float*)d_in[2];
    const float* bq   = (const float*)d_in[3];
    const float* Wk   = (const float*)d_in[4];
    const float* bk   = (const float*)d_in[5];
    const float* Wv   = (const float*)d_in[6];
    const float* bv   = (const float*)d_in[7];
    float* out = (float*)d_out;

    fused_attn_kernel<<<512, 256, 0, stream>>>(
        x, Wq, bq, Wk, bk, Wv, bv, vlen, out);
}

// Round 12
// 105.587 us; speedup vs baseline: 1.9661x; 1.0887x over previous
//
#include <hip/hip_runtime.h>
#include <stdint.h>

// Problem constants: B=32, N=1024, C=64, G=64
//
// R12: barrier-free fused kernel, v2.
//  - K/V recompute per tile uses hi-only fp16 (x_hi*W_hi): 32 MFMA/tile/wave
//    (was 64). Q keeps full split precision (one-time, prologue).
//  - 2 barriers/tile (was 4): XH double-buffered, KL/PS dedicated buffers.
//  - x(t+1) prefetched into registers before barrier A (global latency hidden).
//
// LDS (64 KB, shorts):
//   Q   [    0, 4096)  q tile, A-layout staged (resident)
//   VS  [ 4096, 8192)  V^T tile [g][key]  (written T3, read T5)
//   XH0 [ 8192,12288)  x_hi buffer 0      (prologue: q's x_hi)
//   XH1 [12288,16384)  x_hi buffer 1
//   KL  [16384,20480)  k tile, A-layout   (prologue: q's x_lo)
//   PS  [20480,24576)  P matrix fp16      (prologue: Wq_lo)
//   WK0 [24576,28672)  Wk_hi (resident)   (prologue: Wq_hi)
//   WV0 [28672,32768)  Wv_hi (resident)

typedef __attribute__((ext_vector_type(4))) float    floatx4;
typedef __attribute__((ext_vector_type(8))) _Float16 halfx8;

static __device__ __forceinline__ unsigned short f2h(float f) {
    union { _Float16 h; unsigned short u; } v; v.h = (_Float16)f;
    return v.u;
}
static __device__ __forceinline__ float h2f(unsigned short u) {
    union { unsigned short u; _Float16 h; } v; v.u = u;
    return (float)v.h;
}

// stage W^T (64x64) hi+lo planes, swizzled.
static __device__ __forceinline__ void stage_w_split(
    const float* __restrict__ W, unsigned short* hiDst, unsigned short* loDst,
    int tid)
{
    int g = tid & 63, ci = tid >> 6;
#pragma unroll
    for (int j = 0; j < 16; ++j) {
        int c = ci * 16 + j;
        float f = W[c * 64 + g];
        unsigned short hi = f2h(f);
        int idx = g * 64 + (((c >> 3) ^ (g & 7)) * 8) + (c & 7);
        hiDst[idx] = hi;
        loDst[idx] = f2h(f - h2f(hi));
    }
}
// stage W^T hi only.
static __device__ __forceinline__ void stage_w_hi(
    const float* __restrict__ W, unsigned short* hiDst, int tid)
{
    int g = tid & 63, ci = tid >> 6;
#pragma unroll
    for (int j = 0; j < 16; ++j) {
        int c = ci * 16 + j;
        int idx = g * 64 + (((c >> 3) ^ (g & 7)) * 8) + (c & 7);
        hiDst[idx] = f2h(W[c * 64 + g]);
    }
}
// stage 64 rows of x as hi-only fp16, swizzled.
static __device__ __forceinline__ void stage_x_hi(
    unsigned short* xh, const float* __restrict__ x, int grow0, int tid)
{
#pragma unroll
    for (int i = 0; i < 2; ++i) {
        int id = i * 256 + tid;
        int r = id >> 3, c8 = id & 7;
        const float4* gp = (const float4*)(x + (grow0 + r) * 64 + c8 * 8);
        float4 f0 = gp[0], f1 = gp[1];
        float fv[8] = { f0.x, f0.y, f0.z, f0.w, f1.x, f1.y, f1.z, f1.w };
        __align__(16) unsigned short thi[8];
#pragma unroll
        for (int j = 0; j < 8; ++j) thi[j] = f2h(fv[j]);
        *(uint4*)&xh[r * 64 + ((c8 ^ (r & 7)) * 8)] = *(uint4*)thi;
    }
}

__global__ __launch_bounds__(256, 2) void fused_attn_kernel(
    const float* __restrict__ x,
    const float* __restrict__ Wq, const float* __restrict__ bq,
    const float* __restrict__ Wk, const float* __restrict__ bk,
    const float* __restrict__ Wv, const float* __restrict__ bv,
    const int* __restrict__ valid_len, float* __restrict__ out)
{
    __shared__ __align__(16) unsigned short smem[8 * 4096];   // 64 KB

    unsigned short* Q   = &smem[0];
    unsigned short* VS  = &smem[4096];
    unsigned short* XH0 = &smem[8192];
    unsigned short* XH1 = &smem[12288];
    unsigned short* KL  = &smem[16384];
    unsigned short* PS  = &smem[20480];
    unsigned short* WK0 = &smem[24576];
    unsigned short* WV0 = &smem[28672];

    const int tid  = threadIdx.x;
    const int blk  = blockIdx.x;          // 0..511
    const int row0 = blk * 64;            // b*1024 + n0
    const int b    = blk >> 4;
    const int lane = tid & 63;
    const int w    = tid >> 6;
    const int l15  = lane & 15;
    const int quad = lane >> 4;
    const int arow = w * 16 + l15;
    const int aidx0 = arow * 64 + (((0 + quad) ^ (arow & 7)) * 8);
    const int aidx1 = arow * 64 + (((4 + quad) ^ (arow & 7)) * 8);

    const int vl    = valid_len[b];
    const int nt    = (vl == 0) ? 16 : ((vl + 63) >> 6);   // vl==0 -> all masked -> uniform
    const int fullt = vl >> 6;

    // ============== Prologue: project own Q-tile (full split) ==============
    // x split: XH0 = hi, KL = lo (temp)
#pragma unroll
    for (int i = 0; i < 2; ++i) {
        int id = i * 256 + tid;
        int r = id >> 3, c8 = id & 7;
        const float4* gp = (const float4*)(x + (row0 + r) * 64 + c8 * 8);
        float4 f0 = gp[0], f1 = gp[1];
        float fv[8] = { f0.x, f0.y, f0.z, f0.w, f1.x, f1.y, f1.z, f1.w };
        __align__(16) unsigned short thi[8], tlo[8];
#pragma unroll
        for (int j = 0; j < 8; ++j) {
            unsigned short hi = f2h(fv[j]);
            thi[j] = hi;
            tlo[j] = f2h(fv[j] - h2f(hi));
        }
        int idx = r * 64 + ((c8 ^ (r & 7)) * 8);
        *(uint4*)&XH0[idx] = *(uint4*)thi;
        *(uint4*)&KL[idx]  = *(uint4*)tlo;
    }
    stage_w_split(Wq, WK0, PS, tid);      // Wq_hi -> WK0, Wq_lo -> PS (temps)
    __syncthreads();                      // S_P1

    {
        halfx8 ah0 = *(const halfx8*)&XH0[aidx0];
        halfx8 ah1 = *(const halfx8*)&XH0[aidx1];
        halfx8 al0 = *(const halfx8*)&KL[aidx0];
        halfx8 al1 = *(const halfx8*)&KL[aidx1];
#pragma unroll
        for (int gs = 0; gs < 4; ++gs) {
            int brow = gs * 16 + l15;
            float bb = bq[gs * 16 + l15];
            floatx4 acc = { bb, bb, bb, bb };
            int bidx0 = brow * 64 + (((0 + quad) ^ (brow & 7)) * 8);
            int bidx1 = brow * 64 + (((4 + quad) ^ (brow & 7)) * 8);
            halfx8 b_hi0 = *(const halfx8*)&WK0[bidx0];
            halfx8 b_hi1 = *(const halfx8*)&WK0[bidx1];
            halfx8 b_lo0 = *(const halfx8*)&PS[bidx0];
            halfx8 b_lo1 = *(const halfx8*)&PS[bidx1];
            acc = __builtin_amdgcn_mfma_f32_16x16x32_f16(ah0, b_hi0, acc, 0, 0, 0);
            acc = __builtin_amdgcn_mfma_f32_16x16x32_f16(ah1, b_hi1, acc, 0, 0, 0);
            acc = __builtin_amdgcn_mfma_f32_16x16x32_f16(ah0, b_lo0, acc, 0, 0, 0);
            acc = __builtin_amdgcn_mfma_f32_16x16x32_f16(ah1, b_lo1, acc, 0, 0, 0);
            acc = __builtin_amdgcn_mfma_f32_16x16x32_f16(al0, b_hi0, acc, 0, 0, 0);
            acc = __builtin_amdgcn_mfma_f32_16x16x32_f16(al1, b_hi1, acc, 0, 0, 0);
            // q (D-layout) -> Q (A-layout staged, wave-private rows)
            int c8 = gs * 2 + (l15 >> 3);
#pragma unroll
            for (int r = 0; r < 4; ++r) {
                int row = w * 16 + quad * 4 + r;
                Q[row * 64 + ((c8 ^ (row & 7)) * 8) + (l15 & 7)] = f2h(acc[r]);
            }
        }
    }
    __syncthreads();                      // S_P2: Q written; all temp reads done

    // resident hi-only W planes + key-tile 0 x_hi (overwrites prologue temps)
    stage_w_hi(Wk, WK0, tid);
    stage_w_hi(Wv, WV0, tid);
    stage_x_hi(XH0, x, b * 1024 + 0, tid);
    // (visible to all after the loop's first barrier A)

    halfx8 aq0 = *(const halfx8*)&Q[aidx0];   // own-wave rows, written above
    halfx8 aq1 = *(const halfx8*)&Q[aidx1];

    float m_r[4]    = { -INFINITY, -INFINITY, -INFINITY, -INFINITY };
    float l_lane[4] = { 0.f, 0.f, 0.f, 0.f };
    floatx4 o[4] = { {0,0,0,0}, {0,0,0,0}, {0,0,0,0}, {0,0,0,0} };

    // staging coords (2 chunks/thread)
    const int r_a  = tid >> 3,          c8_a = tid & 7;
    const int r_b  = (256 + tid) >> 3,  c8_b = tid & 7;
    const int lidx_a = r_a * 64 + ((c8_a ^ (r_a & 7)) * 8);
    const int lidx_b = r_b * 64 + ((c8_b ^ (r_b & 7)) * 8);

    // ========================= K-tile loop (2 barriers) ====================
    for (int t = 0; t < nt; ++t) {
        bool pre = (t + 1) < nt;
        float4 pf[4];
        if (pre) {
            const float* xp = x + (b * 1024 + (t + 1) * 64) * 64;
            pf[0] = ((const float4*)(xp + r_a * 64 + c8_a * 8))[0];
            pf[1] = ((const float4*)(xp + r_a * 64 + c8_a * 8))[1];
            pf[2] = ((const float4*)(xp + r_b * 64 + c8_b * 8))[0];
            pf[3] = ((const float4*)(xp + r_b * 64 + c8_b * 8))[1];
        }
        __syncthreads();                  // A: prior VS/KL/PS reads + old XH reads done
        if (pre) {
            unsigned short* xn = ((t + 1) & 1) ? XH1 : XH0;
            __align__(16) unsigned short ta[8] = {
                f2h(pf[0].x), f2h(pf[0].y), f2h(pf[0].z), f2h(pf[0].w),
                f2h(pf[1].x), f2h(pf[1].y), f2h(pf[1].z), f2h(pf[1].w) };
            __align__(16) unsigned short tb[8] = {
                f2h(pf[2].x), f2h(pf[2].y), f2h(pf[2].z), f2h(pf[2].w),
                f2h(pf[3].x), f2h(pf[3].y), f2h(pf[3].z), f2h(pf[3].w) };
            *(uint4*)&xn[lidx_a] = *(uint4*)ta;
            *(uint4*)&xn[lidx_b] = *(uint4*)tb;
        }
        const unsigned short* XHc = (t & 1) ? XH1 : XH0;
        halfx8 kxh0 = *(const halfx8*)&XHc[aidx0];
        halfx8 kxh1 = *(const halfx8*)&XHc[aidx1];

        // T3: recompute K(t), V(t) hi-only (8+8 MFMA/wave)
        {
#pragma unroll
            for (int gs = 0; gs < 4; ++gs) {
                int brow = gs * 16 + l15;
                int bidx0 = brow * 64 + (((0 + quad) ^ (brow & 7)) * 8);
                int bidx1 = brow * 64 + (((4 + quad) ^ (brow & 7)) * 8);
                float bbk = bk[gs * 16 + l15];
                float bbv = bv[gs * 16 + l15];
                floatx4 kacc = { bbk, bbk, bbk, bbk };
                floatx4 vacc = { bbv, bbv, bbv, bbv };
                kacc = __builtin_amdgcn_mfma_f32_16x16x32_f16(kxh0, *(const halfx8*)&WK0[bidx0], kacc, 0, 0, 0);
                kacc = __builtin_amdgcn_mfma_f32_16x16x32_f16(kxh1, *(const halfx8*)&WK0[bidx1], kacc, 0, 0, 0);
                vacc = __builtin_amdgcn_mfma_f32_16x16x32_f16(kxh0, *(const halfx8*)&WV0[bidx0], vacc, 0, 0, 0);
                vacc = __builtin_amdgcn_mfma_f32_16x16x32_f16(kxh1, *(const halfx8*)&WV0[bidx1], vacc, 0, 0, 0);
                int c8 = gs * 2 + (l15 >> 3);
                int g  = gs * 16 + l15;
#pragma unroll
                for (int r = 0; r < 4; ++r) {
                    int key = w * 16 + quad * 4 + r;
                    KL[key * 64 + ((c8 ^ (key & 7)) * 8) + (l15 & 7)] = f2h(kacc[r]);
                    VS[g * 64 + (((key >> 3) ^ (g & 7)) * 8) + (key & 7)] = f2h(vacc[r]);
                }
            }
        }
        __syncthreads();                  // B: K/V tiles + next XH visible

        // T4: S = Q K^T
        floatx4 s[4];
#pragma unroll
        for (int sub = 0; sub < 4; ++sub) {
            int krow = sub * 16 + l15;
            halfx8 bk0 = *(const halfx8*)&KL[krow * 64 + (((0 + quad) ^ (krow & 7)) * 8)];
            halfx8 bk1 = *(const halfx8*)&KL[krow * 64 + (((4 + quad) ^ (krow & 7)) * 8)];
            floatx4 acc = { 0, 0, 0, 0 };
            acc = __builtin_amdgcn_mfma_f32_16x16x32_f16(aq0, bk0, acc, 0, 0, 0);
            acc = __builtin_amdgcn_mfma_f32_16x16x32_f16(aq1, bk1, acc, 0, 0, 0);
            s[sub] = acc;
        }
        if (t >= fullt) {
#pragma unroll
            for (int sub = 0; sub < 4; ++sub) {
                int key = t * 64 + sub * 16 + l15;
                if (key >= vl) { s[sub][0] = -1e6f; s[sub][1] = -1e6f; s[sub][2] = -1e6f; s[sub][3] = -1e6f; }
            }
        }

        // online softmax: wave-consistent max; per-lane deferred sum
        float p[4][4];
        float alpha[4];
#pragma unroll
        for (int r = 0; r < 4; ++r) {
            float mx = fmaxf(fmaxf(s[0][r], s[1][r]), fmaxf(s[2][r], s[3][r]));
#pragma unroll
            for (int off = 1; off < 16; off <<= 1)
                mx = fmaxf(mx, __shfl_xor(mx, off, 64));
            float mnew = fmaxf(m_r[r], mx);
            alpha[r] = __expf(m_r[r] - mnew);
            float psum = 0.f;
#pragma unroll
            for (int sub = 0; sub < 4; ++sub) {
                float pv = __expf(s[sub][r] - mnew);
                p[sub][r] = pv;
                psum += pv;
            }
            l_lane[r] = l_lane[r] * alpha[r] + psum;
            m_r[r] = mnew;
        }
#pragma unroll
        for (int gs = 0; gs < 4; ++gs) {
            o[gs][0] *= alpha[0]; o[gs][1] *= alpha[1];
            o[gs][2] *= alpha[2]; o[gs][3] *= alpha[3];
        }

        // P (D-layout) -> fp16 LDS (A-layout, wave-private region of PS)
        unsigned short* psw = &PS[w * 1024];
#pragma unroll
        for (int sub = 0; sub < 4; ++sub) {
            int c8 = sub * 2 + (l15 >> 3);
#pragma unroll
            for (int r = 0; r < 4; ++r) {
                int row = quad * 4 + r;
                psw[row * 64 + ((c8 ^ (row & 7)) * 8) + (l15 & 7)] = f2h(p[sub][r]);
            }
        }
        halfx8 ap0 = *(const halfx8*)&psw[l15 * 64 + (((0 + quad) ^ (l15 & 7)) * 8)];
        halfx8 ap1 = *(const halfx8*)&psw[l15 * 64 + (((4 + quad) ^ (l15 & 7)) * 8)];

        // T5: O += P V
#pragma unroll
        for (int gs = 0; gs < 4; ++gs) {
            int grow = gs * 16 + l15;
            halfx8 bv0 = *(const halfx8*)&VS[grow * 64 + (((0 + quad) ^ (grow & 7)) * 8)];
            halfx8 bv1 = *(const halfx8*)&VS[grow * 64 + (((4 + quad) ^ (grow & 7)) * 8)];
            o[gs] = __builtin_amdgcn_mfma_f32_16x16x32_f16(ap0, bv0, o[gs], 0, 0, 0);
            o[gs] = __builtin_amdgcn_mfma_f32_16x16x32_f16(ap1, bv1, o[gs], 0, 0, 0);
        }
    }

    // ---- final 16-lane sum butterfly, store ----
    float l[4];
#pragma unroll
    for (int r = 0; r < 4; ++r) {
        float ss = l_lane[r];
#pragma unroll
        for (int off = 1; off < 16; off <<= 1)
            ss += __shfl_xor(ss, off, 64);
        l[r] = ss;
    }
#pragma unroll
    for (int gs = 0; gs < 4; ++gs) {
#pragma unroll
        for (int r = 0; r < 4; ++r) {
            int row = row0 + w * 16 + quad * 4 + r;
            out[row * 64 + gs * 16 + l15] = o[gs][r] / l[r];
        }
    }
}

// ---------------------------------------------------------------------------
extern "C" void kernel_launch(void* const* d_in, const int* in_sizes, int n_in,
                              void* d_out, int out_size, void* d_ws, size_t ws_size,
                              hipStream_t stream) {
    const float* x    = (const float*)d_in[0];
    const int*   vlen = (const int*)  d_in[1];
    const float* Wq   = (const float*)d_in[2];
    const float* bq   = (const float*)d_in[3];
    const float* Wk   = (const float*)d_in[4];
    const float* bk   = (const float*)d_in[5];
    const float* Wv   = (const float*)d_in[6];
    const float* bv   = (const float*)d_in[7];
    float* out = (float*)d_out;

    fused_attn_kernel<<<512, 256, 0, stream>>>(
        x, Wq, bq, Wk, bk, Wv, bv, vlen, out);
}